// Round 7
// baseline (405.934 us; speedup 1.0000x reference)
//
#include <hip/hip_runtime.h>

typedef unsigned short u16;
typedef __attribute__((ext_vector_type(8))) short short8;
typedef __attribute__((ext_vector_type(4))) float f32x4;

#define A_ 4
#define T_ 128
#define B_ 256
#define OBS_ 128
#define H_ 128
#define G_ 384
#define ACT_ 8

__device__ __forceinline__ u16 f2b(float x) {
    unsigned int u = __float_as_uint(x);
    u = (u + 0x7fffu + ((u >> 16) & 1u)) >> 16;
    return (u16)u;
}
__device__ __forceinline__ u16 f2bc(float x) {  // cheap RN (ties up) for hot loop
    return (u16)((__float_as_uint(x) + 0x8000u) >> 16);
}
__device__ __forceinline__ float b2f(u16 h) {
    return __uint_as_float(((unsigned int)h) << 16);
}
__device__ __forceinline__ float fexp2_(float x) { return __builtin_amdgcn_exp2f(x); }
__device__ __forceinline__ float frcp_(float x) { return __builtin_amdgcn_rcpf(x); }
__device__ __forceinline__ float sigmoidf_(float x) {
    return frcp_(1.0f + fexp2_(-1.4426950408889634f * x));
}
__device__ __forceinline__ float tanhf_(float x) {
    return 1.0f - 2.0f * frcp_(1.0f + fexp2_(2.8853900817779268f * x));
}
__device__ __forceinline__ f32x4 mfma16(short8 a, short8 b, f32x4 c) {
    return __builtin_amdgcn_mfma_f32_16x16x32_bf16(a, b, c, 0, 0, 0);
}
// Block barrier WITHOUT the vmcnt(0)/expcnt(0) drain __syncthreads() emits.
__device__ __forceinline__ void barrier_fast() {
    asm volatile("s_waitcnt lgkmcnt(0)\n\ts_barrier" ::: "memory");
}

// ---------------- K0: weight transpose/convert + std output ----------------
__global__ void k_prep(const float* __restrict__ We, const float* __restrict__ Wi,
                       const float* __restrict__ Wh, const float* __restrict__ Wa1,
                       const float* __restrict__ Wc1, const float* __restrict__ Wa2,
                       const float* __restrict__ Wc2, const float* __restrict__ log_std,
                       u16* __restrict__ weT, u16* __restrict__ wiT, u16* __restrict__ whT,
                       u16* __restrict__ wa1T, u16* __restrict__ wc1T, u16* __restrict__ h2T,
                       float* __restrict__ std_out) {
    const int PER_A = 149504;
    int idx = blockIdx.x * 256 + threadIdx.x;
    const int total = 4 * PER_A;
    if (idx < total) {
        int a = idx / PER_A;
        int i = idx % PER_A;
        if (i < 16384) {
            int h = i >> 7, o = i & 127;
            weT[a * 16384 + i] = f2b(We[a * 16384 + o * 128 + h]);
        } else if (i < 16384 + 49152) {
            int j = i - 16384; int g = j >> 7, k = j & 127;
            wiT[a * 49152 + j] = f2b(Wi[a * 49152 + k * 384 + g]);
        } else if (i < 16384 + 2 * 49152) {
            int j = i - 16384 - 49152; int g = j >> 7, k = j & 127;
            whT[a * 49152 + j] = f2b(Wh[a * 49152 + k * 384 + g]);
        } else if (i < 2 * 16384 + 2 * 49152) {
            int j = i - 16384 - 2 * 49152; int h2 = j >> 7, k = j & 127;
            wa1T[a * 16384 + j] = f2b(Wa1[a * 16384 + k * 128 + h2]);
        } else if (i < 3 * 16384 + 2 * 49152) {
            int j = i - 2 * 16384 - 2 * 49152; int h2 = j >> 7, k = j & 127;
            wc1T[a * 16384 + j] = f2b(Wc1[a * 16384 + k * 128 + h2]);
        } else {
            int j = i - 3 * 16384 - 2 * 49152; int row = j >> 7, k = j & 127;
            float v = 0.f;
            if (row < 8) v = Wa2[a * 1024 + k * 8 + row];
            else if (row == 8) v = Wc2[a * 128 + k];
            h2T[a * 2048 + j] = f2b(v);
        }
    } else if (idx < total + 32) {
        int i = idx - total;
        std_out[i] = __expf(log_std[i]);
    }
}

// ---------------- K1: fused emb/xi, weight-stationary ----------------------
__global__ __launch_bounds__(512, 2) void k_embed_xi(
    const float* __restrict__ obs, const float* __restrict__ be, const float* __restrict__ bi,
    const u16* __restrict__ weT, const u16* __restrict__ wiT, u16* __restrict__ xi_ws) {
    __shared__ __align__(16) u16 obsl[16][136];
    __shared__ __align__(16) u16 elds[16][136];
    const int a = blockIdx.y, t = blockIdx.x;
    const int wid = threadIdx.x >> 6, lane = threadIdx.x & 63;
    const int m = lane & 15, quad = lane >> 4;
    const int srow = threadIdx.x >> 5, schunk = threadIdx.x & 31;

    short8 we[4], wi[3][4];
    {
        const u16* p = weT + a * 16384 + (wid * 16 + m) * 128 + quad * 8;
#pragma unroll
        for (int ks = 0; ks < 4; ++ks) we[ks] = *(const short8*)(p + ks * 32);
#pragma unroll
        for (int g = 0; g < 3; ++g) {
            const u16* q = wiT + a * 49152 + (g * 128 + wid * 16 + m) * 128 + quad * 8;
#pragma unroll
            for (int ks = 0; ks < 4; ++ks) wi[g][ks] = *(const short8*)(q + ks * 32);
        }
    }
    const float bee = be[a * H_ + wid * 16 + m];
    float big[3];
#pragma unroll
    for (int g = 0; g < 3; ++g) big[g] = bi[a * G_ + g * 128 + wid * 16 + m];

    const float* obsrow = obs + ((size_t)(a * T_ + t) * B_ + srow) * OBS_ + schunk * 4;
    float4 pf = *(const float4*)(obsrow);
    ushort4* xi4 = (ushort4*)xi_ws;

    for (int it = 0; it < 16; ++it) {
        ushort4 ob;
        ob.x = f2b(pf.x); ob.y = f2b(pf.y); ob.z = f2b(pf.z); ob.w = f2b(pf.w);
        *(ushort4*)&obsl[srow][schunk * 4] = ob;
        barrier_fast();
        if (it + 1 < 16) pf = *(const float4*)(obsrow + (size_t)(it + 1) * 2048);

        short8 af[4];
#pragma unroll
        for (int ks = 0; ks < 4; ++ks)
            af[ks] = *(const short8*)&obsl[m][ks * 32 + quad * 8];
        f32x4 acc = f32x4{0.f, 0.f, 0.f, 0.f};
#pragma unroll
        for (int ks = 0; ks < 4; ++ks) acc = mfma16(af[ks], we[ks], acc);
#pragma unroll
        for (int r = 0; r < 4; ++r)
            elds[quad * 4 + r][wid * 16 + m] = f2b(tanhf_(acc[r] + bee));
        barrier_fast();

        short8 ef[4];
#pragma unroll
        for (int ks = 0; ks < 4; ++ks)
            ef[ks] = *(const short8*)&elds[m][ks * 32 + quad * 8];
        f32x4 xa[3];
#pragma unroll
        for (int g = 0; g < 3; ++g) xa[g] = f32x4{0.f, 0.f, 0.f, 0.f};
#pragma unroll
        for (int ks = 0; ks < 4; ++ks)
#pragma unroll
            for (int g = 0; g < 3; ++g) xa[g] = mfma16(ef[ks], wi[g][ks], xa[g]);

        const size_t base = ((size_t)(a * 16 + it) * T_ + t) * 1536;
#pragma unroll
        for (int g = 0; g < 3; ++g) {
            ushort4 pk;
            pk.x = f2b(xa[g][0] + big[g]);
            pk.y = f2b(xa[g][1] + big[g]);
            pk.z = f2b(xa[g][2] + big[g]);
            pk.w = f2b(xa[g][3] + big[g]);
            xi4[base + (size_t)(wid * 3 + g) * 64 + lane] = pk;
        }
    }
}

// ---------------- K2: GRU scan, 2 chains PER WAVE ---------------------------
// 32 blocks x 8 waves (512 thr). Each wave handles its 16-col slice of TWO
// independent btiles of the SAME agent (shared Wh fragments). The two
// instruction streams are independent, so the compiler interleaves them:
// chain B's VALU/MFMA issues while chain A's ds_read/MFMA/transcendental
// chains wait. One barrier per step serves both chains (intra-wave ILP does
// the stall-filling, not wave arbitration -- round 3's failure mode).
// r/z MFMA accumulators are seeded with xr/xz (C operand), deleting the
// separate zero-init + add.
__global__ __launch_bounds__(512, 2) void k_scan(
    const float* __restrict__ hstate, const u16* __restrict__ xi_ws,
    const u16* __restrict__ whT, const float* __restrict__ bhn,
    const int* __restrict__ done, u16* __restrict__ ys_ws, float* __restrict__ hT_out) {
    __shared__ __align__(16) u16 hlds[2][2][16][136];  // [chain][buf][row][col]
    const int a = blockIdx.y;
    const int wq = threadIdx.x >> 6, lane = threadIdx.x & 63;
    const int m = lane & 15, quad = lane >> 4;
    const int col = 16 * wq + m;

    short8 wh[3][4];
    const u16* whTa = whT + a * 49152;
#pragma unroll
    for (int g = 0; g < 3; ++g) {
        const u16* p = whTa + (g * 128 + col) * 128 + quad * 8;
#pragma unroll
        for (int ks = 0; ks < 4; ++ks) wh[g][ks] = *(const short8*)(p + ks * 32);
    }
    const float bh = bhn[a * H_ + col];

    const int b00 = blockIdx.x * 32;   // chain0 batch base
    const int b01 = b00 + 16;          // chain1 batch base

    float hm0[4], hm1[4]; u16 hb0[4], hb1[4];
#pragma unroll
    for (int r = 0; r < 4; ++r) {
        float v0 = hstate[((size_t)a * B_ + b00 + quad * 4 + r) * H_ + col];
        float v1 = hstate[((size_t)a * B_ + b01 + quad * 4 + r) * H_ + col];
        hm0[r] = v0; hb0[r] = f2b(v0);
        hm1[r] = v1; hb1[r] = f2b(v1);
    }

    const ushort4* xi4 = (const ushort4*)xi_ws;
    const ushort4* xp0 = xi4 + ((size_t)(a * 16 + blockIdx.x * 2) * T_) * 1536 + wq * 192 + lane;
    const ushort4* xp1 = xp0 + (size_t)T_ * 1536;   // next btile
    const int* dp0 = done + (size_t)a * T_ * B_ + b00 + quad * 4;
    const int* dp1 = dp0 + 16;
    u16* yp0 = ys_ws + ((size_t)a * T_ * B_ + b00 + quad * 4) * H_ + col;
    u16* yp1 = yp0 + 16 * H_;

    // 1-step-ahead prefetch (per chain): step time ~1.3k cy >> L2/L3 latency
    ushort4 P00 = xp0[0], P01 = xp0[64], P02 = xp0[128];
    ushort4 P10 = xp1[0], P11 = xp1[64], P12 = xp1[128];
    int4 dn0 = *(const int4*)dp0;
    int4 dn1 = *(const int4*)dp1;
    xp0 += 1536; xp1 += 1536; dp0 += B_; dp1 += B_;

    for (int t = 0; t < T_; ++t) {
        u16(*hl0)[136] = hlds[0][t & 1];
        u16(*hl1)[136] = hlds[1][t & 1];
        // ---- phase 1: done-reset + LDS publish, both chains ----
        if (dn0.x) { hm0[0] = 0.f; hb0[0] = 0; }
        if (dn0.y) { hm0[1] = 0.f; hb0[1] = 0; }
        if (dn0.z) { hm0[2] = 0.f; hb0[2] = 0; }
        if (dn0.w) { hm0[3] = 0.f; hb0[3] = 0; }
        if (dn1.x) { hm1[0] = 0.f; hb1[0] = 0; }
        if (dn1.y) { hm1[1] = 0.f; hb1[1] = 0; }
        if (dn1.z) { hm1[2] = 0.f; hb1[2] = 0; }
        if (dn1.w) { hm1[3] = 0.f; hb1[3] = 0; }
#pragma unroll
        for (int r = 0; r < 4; ++r) {
            hl0[quad * 4 + r][col] = hb0[r];
            hl1[quad * 4 + r][col] = hb1[r];
        }
        barrier_fast();

        // ---- phase 2: x extraction (seeds MFMA C) + next-step prefetch ----
        f32x4 ar0, az0, an0, ar1, az1, an1;
        float xn0[4], xn1[4];
        ar0[0] = b2f(P00.x); ar0[1] = b2f(P00.y); ar0[2] = b2f(P00.z); ar0[3] = b2f(P00.w);
        az0[0] = b2f(P01.x); az0[1] = b2f(P01.y); az0[2] = b2f(P01.z); az0[3] = b2f(P01.w);
        xn0[0] = b2f(P02.x); xn0[1] = b2f(P02.y); xn0[2] = b2f(P02.z); xn0[3] = b2f(P02.w);
        ar1[0] = b2f(P10.x); ar1[1] = b2f(P10.y); ar1[2] = b2f(P10.z); ar1[3] = b2f(P10.w);
        az1[0] = b2f(P11.x); az1[1] = b2f(P11.y); az1[2] = b2f(P11.z); az1[3] = b2f(P11.w);
        xn1[0] = b2f(P12.x); xn1[1] = b2f(P12.y); xn1[2] = b2f(P12.z); xn1[3] = b2f(P12.w);
        an0 = f32x4{0.f, 0.f, 0.f, 0.f};
        an1 = f32x4{0.f, 0.f, 0.f, 0.f};
        if (t + 1 < T_) {
            P00 = xp0[0]; P01 = xp0[64]; P02 = xp0[128]; dn0 = *(const int4*)dp0;
            P10 = xp1[0]; P11 = xp1[64]; P12 = xp1[128]; dn1 = *(const int4*)dp1;
        }
        xp0 += 1536; xp1 += 1536; dp0 += B_; dp1 += B_;

        // ---- phase 3: h@Wh, both chains (independent MFMA chains) ----
        short8 af0[4], af1[4];
#pragma unroll
        for (int ks = 0; ks < 4; ++ks) {
            af0[ks] = *(const short8*)&hl0[m][ks * 32 + quad * 8];
            af1[ks] = *(const short8*)&hl1[m][ks * 32 + quad * 8];
        }
#pragma unroll
        for (int ks = 0; ks < 4; ++ks) {
            ar0 = mfma16(af0[ks], wh[0][ks], ar0);
            ar1 = mfma16(af1[ks], wh[0][ks], ar1);
            az0 = mfma16(af0[ks], wh[1][ks], az0);
            az1 = mfma16(af1[ks], wh[1][ks], az1);
            an0 = mfma16(af0[ks], wh[2][ks], an0);
            an1 = mfma16(af1[ks], wh[2][ks], an1);
        }

        // ---- phase 4: gates + ys store, both chains ----
#pragma unroll
        for (int r = 0; r < 4; ++r) {
            const float rg0 = sigmoidf_(ar0[r]);
            const float zg0 = sigmoidf_(az0[r]);
            const float ng0 = tanhf_(fmaf(rg0, an0[r] + bh, xn0[r]));
            const float h0 = fmaf(zg0, hm0[r] - ng0, ng0);
            hm0[r] = h0; hb0[r] = f2bc(h0);
            yp0[(size_t)r * H_] = hb0[r];
            const float rg1 = sigmoidf_(ar1[r]);
            const float zg1 = sigmoidf_(az1[r]);
            const float ng1 = tanhf_(fmaf(rg1, an1[r] + bh, xn1[r]));
            const float h1 = fmaf(zg1, hm1[r] - ng1, ng1);
            hm1[r] = h1; hb1[r] = f2bc(h1);
            yp1[(size_t)r * H_] = hb1[r];
        }
        yp0 += (size_t)B_ * H_; yp1 += (size_t)B_ * H_;
    }

#pragma unroll
    for (int r = 0; r < 4; ++r) {
        hT_out[((size_t)a * B_ + b00 + quad * 4 + r) * H_ + col] = hm0[r];
        hT_out[((size_t)a * B_ + b01 + quad * 4 + r) * H_ + col] = hm1[r];
    }
}

// ---------------- K3: actor/critic heads, weight-stationary ----------------
__global__ __launch_bounds__(512, 4) void k_heads(
    const u16* __restrict__ ys_ws, const u16* __restrict__ wa1T, const u16* __restrict__ wc1T,
    const u16* __restrict__ h2T, const float* __restrict__ ba1, const float* __restrict__ bc1,
    const float* __restrict__ ba2, const float* __restrict__ bc2,
    float* __restrict__ mean_out, float* __restrict__ val_out) {
    __shared__ __align__(16) u16 ysl[16][136];
    __shared__ __align__(16) u16 al[2][16][136];
    const int a = blockIdx.y;
    const int wid = threadIdx.x >> 6, lane = threadIdx.x & 63;
    const int m = lane & 15, quad = lane >> 4;
    const int srow = threadIdx.x >> 5, schunk = threadIdx.x & 31;

    short8 wa[4], wc[4], h2f[4];
    {
        const u16* pa = wa1T + a * 16384 + (wid * 16 + m) * 128 + quad * 8;
        const u16* pc = wc1T + a * 16384 + (wid * 16 + m) * 128 + quad * 8;
        const u16* ph = h2T + a * 2048 + m * 128 + quad * 8;
#pragma unroll
        for (int ks = 0; ks < 4; ++ks) {
            wa[ks] = *(const short8*)(pa + ks * 32);
            wc[ks] = *(const short8*)(pc + ks * 32);
            h2f[ks] = *(const short8*)(ph + ks * 32);
        }
    }
    const float fa = ba1[a * 128 + wid * 16 + m];
    const float fc = bc1[a * 128 + wid * 16 + m];

    const u16* ysbase = ys_ws + ((size_t)a * 32768 + (size_t)blockIdx.x * 256 + srow) * 128 + schunk * 4;
    ushort4 pf = *(const ushort4*)(ysbase);

    for (int it = 0; it < 16; ++it) {
        *(ushort4*)&ysl[srow][schunk * 4] = pf;
        barrier_fast();
        if (it + 1 < 16) pf = *(const ushort4*)(ysbase + (size_t)(it + 1) * 2048);

        short8 yf[4];
#pragma unroll
        for (int ks = 0; ks < 4; ++ks)
            yf[ks] = *(const short8*)&ysl[m][ks * 32 + quad * 8];
        f32x4 aa = f32x4{0.f, 0.f, 0.f, 0.f};
        f32x4 ac = f32x4{0.f, 0.f, 0.f, 0.f};
#pragma unroll
        for (int ks = 0; ks < 4; ++ks) {
            aa = mfma16(yf[ks], wa[ks], aa);
            ac = mfma16(yf[ks], wc[ks], ac);
        }
#pragma unroll
        for (int r = 0; r < 4; ++r) {
            al[0][quad * 4 + r][wid * 16 + m] = f2b(tanhf_(aa[r] + fa));
            al[1][quad * 4 + r][wid * 16 + m] = f2b(tanhf_(ac[r] + fc));
        }
        barrier_fast();

        if (wid < 2) {
            short8 tf[4];
#pragma unroll
            for (int ks = 0; ks < 4; ++ks)
                tf[ks] = *(const short8*)&al[wid][m][ks * 32 + quad * 8];
            f32x4 tacc = f32x4{0.f, 0.f, 0.f, 0.f};
#pragma unroll
            for (int ks = 0; ks < 4; ++ks) tacc = mfma16(tf[ks], h2f[ks], tacc);
            const size_t R0 = (size_t)a * 32768 + (size_t)(blockIdx.x * 16 + it) * 16;
            if (wid == 0) {
                if (m < 8) {
                    const float bb = ba2[a * 8 + m];
#pragma unroll
                    for (int r = 0; r < 4; ++r)
                        mean_out[(R0 + quad * 4 + r) * 8 + m] = tacc[r] + bb;
                }
            } else {
                if (m == 8) {
                    const float bb = bc2[a];
#pragma unroll
                    for (int r = 0; r < 4; ++r)
                        val_out[R0 + quad * 4 + r] = tacc[r] + bb;
                }
            }
        }
    }
}

extern "C" void kernel_launch(void* const* d_in, const int* in_sizes, int n_in,
                              void* d_out, int out_size, void* d_ws, size_t ws_size,
                              hipStream_t stream) {
    const float* hstate = (const float*)d_in[0];
    const float* obs = (const float*)d_in[1];
    const float* We = (const float*)d_in[3];
    const float* be = (const float*)d_in[4];
    const float* Wi = (const float*)d_in[5];
    const float* bi = (const float*)d_in[6];
    const float* Wh = (const float*)d_in[7];
    const float* bhn = (const float*)d_in[8];
    const float* Wa1 = (const float*)d_in[9];
    const float* ba1 = (const float*)d_in[10];
    const float* Wa2 = (const float*)d_in[11];
    const float* ba2 = (const float*)d_in[12];
    const float* log_std = (const float*)d_in[13];
    const float* Wc1 = (const float*)d_in[14];
    const float* bc1 = (const float*)d_in[15];
    const float* Wc2 = (const float*)d_in[16];
    const float* bc2 = (const float*)d_in[17];
    const int* done = (const int*)d_in[18];

    float* out = (float*)d_out;
    float* hT_out = out;                    // (4,256,128)
    float* mean_out = out + 131072;         // (4,128,256,8)
    float* std_out = out + 1179648;         // (4,8)
    float* val_out = out + 1179680;         // (4,128,256)

    u16* ws = (u16*)d_ws;
    u16* xi = ws;
    u16* ys = xi + 50331648;
    u16* weT = ys + 16777216;
    u16* wiT = weT + 65536;
    u16* whT = wiT + 196608;
    u16* wa1T = whT + 196608;
    u16* wc1T = wa1T + 65536;
    u16* h2T = wc1T + 65536;

    hipLaunchKernelGGL(k_prep, dim3(2337), dim3(256), 0, stream,
                       We, Wi, Wh, Wa1, Wc1, Wa2, Wc2, log_std,
                       weT, wiT, whT, wa1T, wc1T, h2T, std_out);
    hipLaunchKernelGGL(k_embed_xi, dim3(128, 4), dim3(512), 0, stream,
                       obs, be, bi, weT, wiT, xi);
    hipLaunchKernelGGL(k_scan, dim3(8, 4), dim3(512), 0, stream,
                       hstate, xi, whT, bhn, done, ys, hT_out);
    hipLaunchKernelGGL(k_heads, dim3(128, 4), dim3(512), 0, stream,
                       ys, wa1T, wc1T, h2T, ba1, bc1, ba2, bc2, mean_out, val_out);
}

// Round 9
// 317.725 us; speedup vs baseline: 1.2776x; 1.2776x over previous
//
#include <hip/hip_runtime.h>

typedef unsigned short u16;
typedef __attribute__((ext_vector_type(8))) short short8;
typedef __attribute__((ext_vector_type(4))) float f32x4;

#define A_ 4
#define T_ 128
#define B_ 256
#define OBS_ 128
#define H_ 128
#define G_ 384
#define ACT_ 8

__device__ __forceinline__ u16 f2b(float x) {
    unsigned int u = __float_as_uint(x);
    u = (u + 0x7fffu + ((u >> 16) & 1u)) >> 16;
    return (u16)u;
}
__device__ __forceinline__ u16 f2bc(float x) {  // cheap RN (ties up) for hot loop
    return (u16)((__float_as_uint(x) + 0x8000u) >> 16);
}
__device__ __forceinline__ float b2f(u16 h) {
    return __uint_as_float(((unsigned int)h) << 16);
}
__device__ __forceinline__ float fexp2_(float x) { return __builtin_amdgcn_exp2f(x); }
__device__ __forceinline__ float frcp_(float x) { return __builtin_amdgcn_rcpf(x); }
__device__ __forceinline__ float sigmoidf_(float x) {
    return frcp_(1.0f + fexp2_(-1.4426950408889634f * x));
}
__device__ __forceinline__ float tanhf_(float x) {
    return 1.0f - 2.0f * frcp_(1.0f + fexp2_(2.8853900817779268f * x));
}
__device__ __forceinline__ f32x4 mfma16(short8 a, short8 b, f32x4 c) {
    return __builtin_amdgcn_mfma_f32_16x16x32_bf16(a, b, c, 0, 0, 0);
}

// ---------------- K0: weight transpose/convert + std output ----------------
__global__ void k_prep(const float* __restrict__ We, const float* __restrict__ Wi,
                       const float* __restrict__ Wh, const float* __restrict__ Wa1,
                       const float* __restrict__ Wc1, const float* __restrict__ Wa2,
                       const float* __restrict__ Wc2, const float* __restrict__ log_std,
                       u16* __restrict__ weT, u16* __restrict__ wiT, u16* __restrict__ whT,
                       u16* __restrict__ wa1T, u16* __restrict__ wc1T, u16* __restrict__ h2T,
                       float* __restrict__ std_out) {
    const int PER_A = 149504;
    int idx = blockIdx.x * 256 + threadIdx.x;
    const int total = 4 * PER_A;
    if (idx < total) {
        int a = idx / PER_A;
        int i = idx % PER_A;
        if (i < 16384) {
            int h = i >> 7, o = i & 127;
            weT[a * 16384 + i] = f2b(We[a * 16384 + o * 128 + h]);
        } else if (i < 16384 + 49152) {
            int j = i - 16384; int g = j >> 7, k = j & 127;
            wiT[a * 49152 + j] = f2b(Wi[a * 49152 + k * 384 + g]);
        } else if (i < 16384 + 2 * 49152) {
            int j = i - 16384 - 49152; int g = j >> 7, k = j & 127;
            whT[a * 49152 + j] = f2b(Wh[a * 49152 + k * 384 + g]);
        } else if (i < 2 * 16384 + 2 * 49152) {
            int j = i - 16384 - 2 * 49152; int h2 = j >> 7, k = j & 127;
            wa1T[a * 16384 + j] = f2b(Wa1[a * 16384 + k * 128 + h2]);
        } else if (i < 3 * 16384 + 2 * 49152) {
            int j = i - 2 * 16384 - 2 * 49152; int h2 = j >> 7, k = j & 127;
            wc1T[a * 16384 + j] = f2b(Wc1[a * 16384 + k * 128 + h2]);
        } else {
            int j = i - 3 * 16384 - 2 * 49152; int row = j >> 7, k = j & 127;
            float v = 0.f;
            if (row < 8) v = Wa2[a * 1024 + k * 8 + row];
            else if (row == 8) v = Wc2[a * 128 + k];
            h2T[a * 2048 + j] = f2b(v);
        }
    } else if (idx < total + 32) {
        int i = idx - total;
        std_out[i] = __expf(log_std[i]);
    }
}

// ---------------- K1: fused emb/xi, weight-stationary (round-0 form) -------
__global__ __launch_bounds__(512) void k_embed_xi(
    const float* __restrict__ obs, const float* __restrict__ be, const float* __restrict__ bi,
    const u16* __restrict__ weT, const u16* __restrict__ wiT, u16* __restrict__ xi_ws) {
    __shared__ __align__(16) u16 obsl[16][136];
    __shared__ __align__(16) u16 elds[16][136];
    const int a = blockIdx.y, t = blockIdx.x;
    const int wid = threadIdx.x >> 6, lane = threadIdx.x & 63;
    const int m = lane & 15, quad = lane >> 4;
    const int srow = threadIdx.x >> 5, schunk = threadIdx.x & 31;

    short8 we[4], wi[3][4];
    {
        const u16* p = weT + a * 16384 + (wid * 16 + m) * 128 + quad * 8;
#pragma unroll
        for (int ks = 0; ks < 4; ++ks) we[ks] = *(const short8*)(p + ks * 32);
#pragma unroll
        for (int g = 0; g < 3; ++g) {
            const u16* q = wiT + a * 49152 + (g * 128 + wid * 16 + m) * 128 + quad * 8;
#pragma unroll
            for (int ks = 0; ks < 4; ++ks) wi[g][ks] = *(const short8*)(q + ks * 32);
        }
    }
    const float bee = be[a * H_ + wid * 16 + m];
    float big[3];
#pragma unroll
    for (int g = 0; g < 3; ++g) big[g] = bi[a * G_ + g * 128 + wid * 16 + m];

    const float* obsrow = obs + ((size_t)(a * T_ + t) * B_ + srow) * OBS_ + schunk * 4;
    float4 pf = *(const float4*)(obsrow);
    ushort4* xi4 = (ushort4*)xi_ws;

    for (int it = 0; it < 16; ++it) {
        ushort4 ob;
        ob.x = f2b(pf.x); ob.y = f2b(pf.y); ob.z = f2b(pf.z); ob.w = f2b(pf.w);
        *(ushort4*)&obsl[srow][schunk * 4] = ob;
        __syncthreads();
        if (it + 1 < 16) pf = *(const float4*)(obsrow + (size_t)(it + 1) * 2048);

        short8 af[4];
#pragma unroll
        for (int ks = 0; ks < 4; ++ks)
            af[ks] = *(const short8*)&obsl[m][ks * 32 + quad * 8];
        f32x4 acc = f32x4{0.f, 0.f, 0.f, 0.f};
#pragma unroll
        for (int ks = 0; ks < 4; ++ks) acc = mfma16(af[ks], we[ks], acc);
#pragma unroll
        for (int r = 0; r < 4; ++r)
            elds[quad * 4 + r][wid * 16 + m] = f2b(tanhf_(acc[r] + bee));
        __syncthreads();

        short8 ef[4];
#pragma unroll
        for (int ks = 0; ks < 4; ++ks)
            ef[ks] = *(const short8*)&elds[m][ks * 32 + quad * 8];
        f32x4 xa[3];
#pragma unroll
        for (int g = 0; g < 3; ++g) xa[g] = f32x4{0.f, 0.f, 0.f, 0.f};
#pragma unroll
        for (int ks = 0; ks < 4; ++ks)
#pragma unroll
            for (int g = 0; g < 3; ++g) xa[g] = mfma16(ef[ks], wi[g][ks], xa[g]);

        const size_t base = ((size_t)(a * 16 + it) * T_ + t) * 1536;
#pragma unroll
        for (int g = 0; g < 3; ++g) {
            ushort4 pk;
            pk.x = f2b(xa[g][0] + big[g]);
            pk.y = f2b(xa[g][1] + big[g]);
            pk.z = f2b(xa[g][2] + big[g]);
            pk.w = f2b(xa[g][3] + big[g]);
            xi4[base + (size_t)(wid * 3 + g) * 64 + lane] = pk;
        }
    }
}

// ---------------- K2: GRU scan + FUSED actor/critic heads ------------------
// Round-0 scan core (64 blocks x 8 waves, 1-deep prefetch, __syncthreads).
// Heads fused: the published h-tile at step t IS ys(t-1) in A-fragment
// layout, so the heads' first GEMMs are 8 extra MFMAs on the same af regs.
// The h published is UNRESET ys; the done-reset for the Wh path is applied
// per-lane (batch row = lane&15) via cndmask after the LDS read. Heads work
// is off the serial h-spine and issues into the scan's stall windows.
// Eliminates k_heads and the 33 MB ys global write entirely.
__global__ __launch_bounds__(512, 2) void k_scan(
    const float* __restrict__ hstate, const u16* __restrict__ xi_ws,
    const u16* __restrict__ whT, const float* __restrict__ bhn,
    const int* __restrict__ done,
    const u16* __restrict__ wa1T, const u16* __restrict__ wc1T, const u16* __restrict__ h2T,
    const float* __restrict__ ba1, const float* __restrict__ bc1,
    const float* __restrict__ ba2, const float* __restrict__ bc2,
    float* __restrict__ hT_out, float* __restrict__ mean_out, float* __restrict__ val_out) {
    __shared__ __align__(16) u16 hlds[2][16][136];
    __shared__ __align__(16) u16 al[2][2][16][136];  // [t&1][head][row][col]
    const int a = blockIdx.y, btile = blockIdx.x;
    const int wid = threadIdx.x >> 6, lane = threadIdx.x & 63;
    const int m = lane & 15, quad = lane >> 4;
    const int b0 = btile * 16;
    const int col = 16 * wid + m;

    short8 wh[3][4];
    const u16* whTa = whT + a * 49152;
#pragma unroll
    for (int g = 0; g < 3; ++g) {
        const u16* p = whTa + (g * 128 + col) * 128 + quad * 8;
#pragma unroll
        for (int ks = 0; ks < 4; ++ks) wh[g][ks] = *(const short8*)(p + ks * 32);
    }
    short8 wa[4], wc[4], h2f[4];
    {
        const u16* pa = wa1T + a * 16384 + col * 128 + quad * 8;
        const u16* pc = wc1T + a * 16384 + col * 128 + quad * 8;
        const u16* ph = h2T + a * 2048 + m * 128 + quad * 8;
#pragma unroll
        for (int ks = 0; ks < 4; ++ks) {
            wa[ks] = *(const short8*)(pa + ks * 32);
            wc[ks] = *(const short8*)(pc + ks * 32);
            h2f[ks] = *(const short8*)(ph + ks * 32);
        }
    }
    const float bh = bhn[a * H_ + col];
    const float fa = ba1[a * 128 + col];
    const float fc = bc1[a * 128 + col];
    float bb2 = 0.f;
    if (wid == 0) { if (m < 8) bb2 = ba2[a * 8 + m]; }
    else if (wid == 1) { if (m == 8) bb2 = bc2[a]; }

    float hm[4]; u16 hb[4];
#pragma unroll
    for (int r = 0; r < 4; ++r) {
        float v = hstate[((size_t)a * B_ + b0 + quad * 4 + r) * H_ + col];
        hm[r] = v; hb[r] = f2b(v);
    }

    const ushort4* xi4 = (const ushort4*)xi_ws;
    const size_t xibase = ((size_t)(a * 16 + btile) * T_) * 1536 + wid * 192 + lane;
    const int* dptr = done + (size_t)a * T_ * B_ + b0 + quad * 4;   // C-layout rows
    const int* dAq = done + (size_t)a * T_ * B_ + b0 + m;           // A-layout row (lane&15)

    ushort4 px0 = xi4[xibase], px1 = xi4[xibase + 64], px2 = xi4[xibase + 128];
    int4 dn = *(const int4*)(dptr);
    int dead = dAq[0];

    for (int t = 0; t < T_; ++t) {
        u16 (*hl)[136] = hlds[t & 1];
        // publish UNRESET ys(t-1) (t=0: hstate)
#pragma unroll
        for (int r = 0; r < 4; ++r) hl[quad * 4 + r][col] = hb[r];
        // reset hm (register copy) for the z*h gate term
        if (dn.x) hm[0] = 0.f;
        if (dn.y) hm[1] = 0.f;
        if (dn.z) hm[2] = 0.f;
        if (dn.w) hm[3] = 0.f;
        __syncthreads();

        // xi extraction seeds the r/z MFMA accumulators
        f32x4 ar, az, an;
        float xn[4];
        ar[0] = b2f(px0.x); ar[1] = b2f(px0.y); ar[2] = b2f(px0.z); ar[3] = b2f(px0.w);
        az[0] = b2f(px1.x); az[1] = b2f(px1.y); az[2] = b2f(px1.z); az[3] = b2f(px1.w);
        xn[0] = b2f(px2.x); xn[1] = b2f(px2.y); xn[2] = b2f(px2.z); xn[3] = b2f(px2.w);
        an = f32x4{0.f, 0.f, 0.f, 0.f};
        const int deadcur = dead;
        if (t + 1 < T_) {
            const size_t nx = xibase + (size_t)(t + 1) * 1536;
            px0 = xi4[nx]; px1 = xi4[nx + 64]; px2 = xi4[nx + 128];
            dn = *(const int4*)(dptr + (size_t)(t + 1) * B_);
            dead = dAq[(size_t)(t + 1) * B_];
        }

        short8 af[4];
#pragma unroll
        for (int ks = 0; ks < 4; ++ks)
            af[ks] = *(const short8*)&hl[m][ks * 32 + quad * 8];

        // heads first GEMMs on UNRESET ys(t-1) — same af registers
        f32x4 aa, ac;
        if (t > 0) {
            aa = f32x4{fa, fa, fa, fa};
            ac = f32x4{fc, fc, fc, fc};
#pragma unroll
            for (int ks = 0; ks < 4; ++ks) {
                aa = mfma16(af[ks], wa[ks], aa);
                ac = mfma16(af[ks], wc[ks], ac);
            }
        }

        // apply done-reset for the Wh path (per-lane batch row)
        const short8 z8 = short8{0, 0, 0, 0, 0, 0, 0, 0};
        short8 afr[4];
#pragma unroll
        for (int ks = 0; ks < 4; ++ks) afr[ks] = deadcur ? z8 : af[ks];
#pragma unroll
        for (int ks = 0; ks < 4; ++ks) {
            ar = mfma16(afr[ks], wh[0][ks], ar);
            az = mfma16(afr[ks], wh[1][ks], az);
            an = mfma16(afr[ks], wh[2][ks], an);
        }

        // heads tanh -> LDS (double-buffered by t&1)
        if (t > 0) {
#pragma unroll
            for (int r = 0; r < 4; ++r) {
                al[t & 1][0][quad * 4 + r][col] = f2b(tanhf_(aa[r]));
                al[t & 1][1][quad * 4 + r][col] = f2b(tanhf_(ac[r]));
            }
            __syncthreads();
        }

        // GRU gates
#pragma unroll
        for (int r = 0; r < 4; ++r) {
            const float rg = sigmoidf_(ar[r]);
            const float zg = sigmoidf_(az[r]);
            const float ng = tanhf_(fmaf(rg, an[r] + bh, xn[r]));
            const float hn2 = fmaf(zg, hm[r] - ng, ng);
            hm[r] = hn2;
            hb[r] = f2bc(hn2);
        }

        // heads second GEMM + output stores (waves 0/1 only, off-spine)
        if (t > 0 && wid < 2) {
            short8 tf[4];
#pragma unroll
            for (int ks = 0; ks < 4; ++ks)
                tf[ks] = *(const short8*)&al[t & 1][wid][m][ks * 32 + quad * 8];
            f32x4 tacc = f32x4{bb2, bb2, bb2, bb2};
#pragma unroll
            for (int ks = 0; ks < 4; ++ks) tacc = mfma16(tf[ks], h2f[ks], tacc);
            const size_t R0 = (size_t)a * 32768 + (size_t)(t - 1) * 256 + b0;
            if (wid == 0) {
                if (m < 8) {
#pragma unroll
                    for (int r = 0; r < 4; ++r)
                        mean_out[(R0 + quad * 4 + r) * 8 + m] = tacc[r];
                }
            } else {
                if (m == 8) {
#pragma unroll
                    for (int r = 0; r < 4; ++r)
                        val_out[R0 + quad * 4 + r] = tacc[r];
                }
            }
        }
    }

#pragma unroll
    for (int r = 0; r < 4; ++r)
        hT_out[((size_t)a * B_ + b0 + quad * 4 + r) * H_ + col] = hm[r];

    // epilogue: heads for ys(T-1)
    {
        u16 (*hl)[136] = hlds[0];
#pragma unroll
        for (int r = 0; r < 4; ++r) hl[quad * 4 + r][col] = hb[r];
        __syncthreads();
        short8 af[4];
#pragma unroll
        for (int ks = 0; ks < 4; ++ks)
            af[ks] = *(const short8*)&hl[m][ks * 32 + quad * 8];
        f32x4 aa = f32x4{fa, fa, fa, fa};
        f32x4 ac = f32x4{fc, fc, fc, fc};
#pragma unroll
        for (int ks = 0; ks < 4; ++ks) {
            aa = mfma16(af[ks], wa[ks], aa);
            ac = mfma16(af[ks], wc[ks], ac);
        }
#pragma unroll
        for (int r = 0; r < 4; ++r) {
            al[0][0][quad * 4 + r][col] = f2b(tanhf_(aa[r]));
            al[0][1][quad * 4 + r][col] = f2b(tanhf_(ac[r]));
        }
        __syncthreads();
        if (wid < 2) {
            short8 tf[4];
#pragma unroll
            for (int ks = 0; ks < 4; ++ks)
                tf[ks] = *(const short8*)&al[0][wid][m][ks * 32 + quad * 8];
            f32x4 tacc = f32x4{bb2, bb2, bb2, bb2};
#pragma unroll
            for (int ks = 0; ks < 4; ++ks) tacc = mfma16(tf[ks], h2f[ks], tacc);
            const size_t R0 = (size_t)a * 32768 + (size_t)(T_ - 1) * 256 + b0;
            if (wid == 0) {
                if (m < 8) {
#pragma unroll
                    for (int r = 0; r < 4; ++r)
                        mean_out[(R0 + quad * 4 + r) * 8 + m] = tacc[r];
                }
            } else {
                if (m == 8) {
#pragma unroll
                    for (int r = 0; r < 4; ++r)
                        val_out[R0 + quad * 4 + r] = tacc[r];
                }
            }
        }
    }
}

extern "C" void kernel_launch(void* const* d_in, const int* in_sizes, int n_in,
                              void* d_out, int out_size, void* d_ws, size_t ws_size,
                              hipStream_t stream) {
    const float* hstate = (const float*)d_in[0];
    const float* obs = (const float*)d_in[1];
    const float* We = (const float*)d_in[3];
    const float* be = (const float*)d_in[4];
    const float* Wi = (const float*)d_in[5];
    const float* bi = (const float*)d_in[6];
    const float* Wh = (const float*)d_in[7];
    const float* bhn = (const float*)d_in[8];
    const float* Wa1 = (const float*)d_in[9];
    const float* ba1 = (const float*)d_in[10];
    const float* Wa2 = (const float*)d_in[11];
    const float* ba2 = (const float*)d_in[12];
    const float* log_std = (const float*)d_in[13];
    const float* Wc1 = (const float*)d_in[14];
    const float* bc1 = (const float*)d_in[15];
    const float* Wc2 = (const float*)d_in[16];
    const float* bc2 = (const float*)d_in[17];
    const int* done = (const int*)d_in[18];

    float* out = (float*)d_out;
    float* hT_out = out;                    // (4,256,128)
    float* mean_out = out + 131072;         // (4,128,256,8)
    float* std_out = out + 1179648;         // (4,8)
    float* val_out = out + 1179680;         // (4,128,256)

    u16* ws = (u16*)d_ws;
    u16* xi = ws;
    u16* ys = xi + 50331648;                // region now unused (kept for layout)
    u16* weT = ys + 16777216;
    u16* wiT = weT + 65536;
    u16* whT = wiT + 196608;
    u16* wa1T = whT + 196608;
    u16* wc1T = wa1T + 65536;
    u16* h2T = wc1T + 65536;

    hipLaunchKernelGGL(k_prep, dim3(2337), dim3(256), 0, stream,
                       We, Wi, Wh, Wa1, Wc1, Wa2, Wc2, log_std,
                       weT, wiT, whT, wa1T, wc1T, h2T, std_out);
    hipLaunchKernelGGL(k_embed_xi, dim3(128, 4), dim3(512), 0, stream,
                       obs, be, bi, weT, wiT, xi);
    hipLaunchKernelGGL(k_scan, dim3(16, 4), dim3(512), 0, stream,
                       hstate, xi, whT, bhn, done,
                       wa1T, wc1T, h2T, ba1, bc1, ba2, bc2,
                       hT_out, mean_out, val_out);
}

// Round 10
// 302.693 us; speedup vs baseline: 1.3411x; 1.0497x over previous
//
#include <hip/hip_runtime.h>

typedef unsigned short u16;
typedef __attribute__((ext_vector_type(8))) short short8;
typedef __attribute__((ext_vector_type(4))) float f32x4;

#define A_ 4
#define T_ 128
#define B_ 256
#define OBS_ 128
#define H_ 128
#define G_ 384
#define ACT_ 8
#define SIGS -1.4426950408889634f
#define TANS 2.8853900817779268f

__device__ __forceinline__ u16 f2b(float x) {
    unsigned int u = __float_as_uint(x);
    u = (u + 0x7fffu + ((u >> 16) & 1u)) >> 16;
    return (u16)u;
}
__device__ __forceinline__ u16 f2bc(float x) {  // cheap RN (ties up) for hot loops
    return (u16)((__float_as_uint(x) + 0x8000u) >> 16);
}
__device__ __forceinline__ float b2f(u16 h) {
    return __uint_as_float(((unsigned int)h) << 16);
}
__device__ __forceinline__ float fexp2_(float x) { return __builtin_amdgcn_exp2f(x); }
__device__ __forceinline__ float frcp_(float x) { return __builtin_amdgcn_rcpf(x); }
// prescaled forms: arg already multiplied by SIGS / TANS at weight-prep time
__device__ __forceinline__ float sig_pre(float x) { return frcp_(1.0f + fexp2_(x)); }
__device__ __forceinline__ float tanh_pre(float x) {
    return fmaf(-2.0f, frcp_(1.0f + fexp2_(x)), 1.0f);
}
__device__ __forceinline__ f32x4 mfma16(short8 a, short8 b, f32x4 c) {
    return __builtin_amdgcn_mfma_f32_16x16x32_bf16(a, b, c, 0, 0, 0);
}

// ---------------- K0: weight transpose/convert (+gate prescale) ------------
__global__ void k_prep(const float* __restrict__ We, const float* __restrict__ Wi,
                       const float* __restrict__ Wh, const float* __restrict__ Wa1,
                       const float* __restrict__ Wc1, const float* __restrict__ Wa2,
                       const float* __restrict__ Wc2, const float* __restrict__ log_std,
                       u16* __restrict__ weT, u16* __restrict__ wiT, u16* __restrict__ whT,
                       u16* __restrict__ wa1T, u16* __restrict__ wc1T, u16* __restrict__ h2T,
                       float* __restrict__ std_out) {
    const int PER_A = 149504;
    int idx = blockIdx.x * 256 + threadIdx.x;
    const int total = 4 * PER_A;
    if (idx < total) {
        int a = idx / PER_A;
        int i = idx % PER_A;
        if (i < 16384) {
            int h = i >> 7, o = i & 127;
            weT[a * 16384 + i] = f2b(TANS * We[a * 16384 + o * 128 + h]);
        } else if (i < 16384 + 49152) {
            int j = i - 16384; int g = j >> 7, k = j & 127;
            float s = (g < 256) ? SIGS : TANS;
            wiT[a * 49152 + j] = f2b(s * Wi[a * 49152 + k * 384 + g]);
        } else if (i < 16384 + 2 * 49152) {
            int j = i - 16384 - 49152; int g = j >> 7, k = j & 127;
            float s = (g < 256) ? SIGS : TANS;
            whT[a * 49152 + j] = f2b(s * Wh[a * 49152 + k * 384 + g]);
        } else if (i < 2 * 16384 + 2 * 49152) {
            int j = i - 16384 - 2 * 49152; int h2 = j >> 7, k = j & 127;
            wa1T[a * 16384 + j] = f2b(TANS * Wa1[a * 16384 + k * 128 + h2]);
        } else if (i < 3 * 16384 + 2 * 49152) {
            int j = i - 2 * 16384 - 2 * 49152; int h2 = j >> 7, k = j & 127;
            wc1T[a * 16384 + j] = f2b(TANS * Wc1[a * 16384 + k * 128 + h2]);
        } else {
            int j = i - 3 * 16384 - 2 * 49152; int row = j >> 7, k = j & 127;
            float v = 0.f;
            if (row < 8) v = Wa2[a * 1024 + k * 8 + row];
            else if (row == 8) v = Wc2[a * 128 + k];
            h2T[a * 2048 + j] = f2b(v);
        }
    } else if (idx < total + 32) {
        int i = idx - total;
        std_out[i] = __expf(log_std[i]);
    }
}

// ---------------- K1: fused emb/xi — split grid, 1 barrier/iter ------------
// grid (128=t, 4=a, 2=half) x 512 thr; each block does 8 btile-iters of its
// half (4 blocks/CU TLP). Software-pipelined: xi GEMM consumes the PREVIOUS
// iteration's elds, so one barrier per iteration. Accumulators seeded with
// (prescaled) biases; tanh via tanh_pre (weights carry the 2.8854 factor).
__global__ __launch_bounds__(512) void k_embed_xi(
    const float* __restrict__ obs, const float* __restrict__ be, const float* __restrict__ bi,
    const u16* __restrict__ weT, const u16* __restrict__ wiT, u16* __restrict__ xi_ws) {
    __shared__ __align__(16) u16 obsl[2][16][136];
    __shared__ __align__(16) u16 elds[2][16][136];
    const int a = blockIdx.y, t = blockIdx.x, half = blockIdx.z;
    const int wid = threadIdx.x >> 6, lane = threadIdx.x & 63;
    const int m = lane & 15, quad = lane >> 4;
    const int srow = threadIdx.x >> 5, schunk = threadIdx.x & 31;

    short8 we[4], wi[3][4];
    {
        const u16* p = weT + a * 16384 + (wid * 16 + m) * 128 + quad * 8;
#pragma unroll
        for (int ks = 0; ks < 4; ++ks) we[ks] = *(const short8*)(p + ks * 32);
#pragma unroll
        for (int g = 0; g < 3; ++g) {
            const u16* q = wiT + a * 49152 + (g * 128 + wid * 16 + m) * 128 + quad * 8;
#pragma unroll
            for (int ks = 0; ks < 4; ++ks) wi[g][ks] = *(const short8*)(q + ks * 32);
        }
    }
    const float bee = TANS * be[a * H_ + wid * 16 + m];
    float big[3];
#pragma unroll
    for (int g = 0; g < 3; ++g)
        big[g] = ((g < 2) ? SIGS : TANS) * bi[a * G_ + g * 128 + wid * 16 + m];

    const float* obsrow = obs + ((size_t)(a * T_ + t) * B_ + half * 128 + srow) * OBS_ + schunk * 4;
    ushort4* xi4 = (ushort4*)xi_ws;

    // prologue: stage iter 0, prefetch iter 1
    {
        float4 p0 = *(const float4*)(obsrow);
        ushort4 ob;
        ob.x = f2b(p0.x); ob.y = f2b(p0.y); ob.z = f2b(p0.z); ob.w = f2b(p0.w);
        *(ushort4*)&obsl[0][srow][schunk * 4] = ob;
    }
    float4 pf = *(const float4*)(obsrow + 2048);
    __syncthreads();

    for (int it = 0; it < 8; ++it) {
        short8 af[4];
#pragma unroll
        for (int ks = 0; ks < 4; ++ks)
            af[ks] = *(const short8*)&obsl[it & 1][m][ks * 32 + quad * 8];
        if (it + 1 < 8) {
            ushort4 ob;
            ob.x = f2b(pf.x); ob.y = f2b(pf.y); ob.z = f2b(pf.z); ob.w = f2b(pf.w);
            *(ushort4*)&obsl[(it + 1) & 1][srow][schunk * 4] = ob;
            if (it + 2 < 8) pf = *(const float4*)(obsrow + (size_t)(it + 2) * 2048);
        }

        f32x4 acc = f32x4{bee, bee, bee, bee};
#pragma unroll
        for (int ks = 0; ks < 4; ++ks) acc = mfma16(af[ks], we[ks], acc);
#pragma unroll
        for (int r = 0; r < 4; ++r)
            elds[it & 1][quad * 4 + r][wid * 16 + m] = f2bc(tanh_pre(acc[r]));

        if (it > 0) {
            short8 ef[4];
#pragma unroll
            for (int ks = 0; ks < 4; ++ks)
                ef[ks] = *(const short8*)&elds[(it - 1) & 1][m][ks * 32 + quad * 8];
            f32x4 xa[3];
#pragma unroll
            for (int g = 0; g < 3; ++g) xa[g] = f32x4{big[g], big[g], big[g], big[g]};
#pragma unroll
            for (int ks = 0; ks < 4; ++ks)
#pragma unroll
                for (int g = 0; g < 3; ++g) xa[g] = mfma16(ef[ks], wi[g][ks], xa[g]);
            const int itg = half * 8 + it - 1;
            const size_t base = ((size_t)(a * 16 + itg) * T_ + t) * 1536;
#pragma unroll
            for (int g = 0; g < 3; ++g) {
                ushort4 pk;
                pk.x = f2bc(xa[g][0]); pk.y = f2bc(xa[g][1]);
                pk.z = f2bc(xa[g][2]); pk.w = f2bc(xa[g][3]);
                xi4[base + (size_t)(wid * 3 + g) * 64 + lane] = pk;
            }
        }
        __syncthreads();
    }
    // epilogue: xi for local iter 7
    {
        short8 ef[4];
#pragma unroll
        for (int ks = 0; ks < 4; ++ks)
            ef[ks] = *(const short8*)&elds[1][m][ks * 32 + quad * 8];
        f32x4 xa[3];
#pragma unroll
        for (int g = 0; g < 3; ++g) xa[g] = f32x4{big[g], big[g], big[g], big[g]};
#pragma unroll
        for (int ks = 0; ks < 4; ++ks)
#pragma unroll
            for (int g = 0; g < 3; ++g) xa[g] = mfma16(ef[ks], wi[g][ks], xa[g]);
        const int itg = half * 8 + 7;
        const size_t base = ((size_t)(a * 16 + itg) * T_ + t) * 1536;
#pragma unroll
        for (int g = 0; g < 3; ++g) {
            ushort4 pk;
            pk.x = f2bc(xa[g][0]); pk.y = f2bc(xa[g][1]);
            pk.z = f2bc(xa[g][2]); pk.w = f2bc(xa[g][3]);
            xi4[base + (size_t)(wid * 3 + g) * 64 + lane] = pk;
        }
    }
}

// ---------------- K2: GRU scan + fused heads, 1 barrier/step ---------------
// Heads' second GEMM deferred one step (al double-buffered by t&1) so the
// per-step al barrier disappears. Gate transcendentals use prescaled args
// (weights carry the exp2 factors); an is MFMA-seeded with bh; done-masking
// skipped when no fragment row is dead.
__global__ __launch_bounds__(512, 2) void k_scan(
    const float* __restrict__ hstate, const u16* __restrict__ xi_ws,
    const u16* __restrict__ whT, const float* __restrict__ bhn,
    const int* __restrict__ done,
    const u16* __restrict__ wa1T, const u16* __restrict__ wc1T, const u16* __restrict__ h2T,
    const float* __restrict__ ba1, const float* __restrict__ bc1,
    const float* __restrict__ ba2, const float* __restrict__ bc2,
    float* __restrict__ hT_out, float* __restrict__ mean_out, float* __restrict__ val_out) {
    __shared__ __align__(16) u16 hlds[2][16][136];
    __shared__ __align__(16) u16 al[2][2][16][136];  // [t&1][head][row][col]
    const int a = blockIdx.y, btile = blockIdx.x;
    const int wid = threadIdx.x >> 6, lane = threadIdx.x & 63;
    const int m = lane & 15, quad = lane >> 4;
    const int b0 = btile * 16;
    const int col = 16 * wid + m;

    short8 wh[3][4];
    const u16* whTa = whT + a * 49152;
#pragma unroll
    for (int g = 0; g < 3; ++g) {
        const u16* p = whTa + (g * 128 + col) * 128 + quad * 8;
#pragma unroll
        for (int ks = 0; ks < 4; ++ks) wh[g][ks] = *(const short8*)(p + ks * 32);
    }
    short8 wa[4], wc[4], h2f[4];
    {
        const u16* pa = wa1T + a * 16384 + col * 128 + quad * 8;
        const u16* pc = wc1T + a * 16384 + col * 128 + quad * 8;
        const u16* ph = h2T + a * 2048 + m * 128 + quad * 8;
#pragma unroll
        for (int ks = 0; ks < 4; ++ks) {
            wa[ks] = *(const short8*)(pa + ks * 32);
            wc[ks] = *(const short8*)(pc + ks * 32);
            h2f[ks] = *(const short8*)(ph + ks * 32);
        }
    }
    const float bh = TANS * bhn[a * H_ + col];
    const float fa = TANS * ba1[a * 128 + col];
    const float fc = TANS * bc1[a * 128 + col];
    float bb2 = 0.f;
    if (wid == 0) { if (m < 8) bb2 = ba2[a * 8 + m]; }
    else if (wid == 1) { if (m == 8) bb2 = bc2[a]; }

    float hm[4]; u16 hb[4];
#pragma unroll
    for (int r = 0; r < 4; ++r) {
        float v = hstate[((size_t)a * B_ + b0 + quad * 4 + r) * H_ + col];
        hm[r] = v; hb[r] = f2b(v);
    }

    const ushort4* xi4 = (const ushort4*)xi_ws;
    const size_t xibase = ((size_t)(a * 16 + btile) * T_) * 1536 + wid * 192 + lane;
    const int* dptr = done + (size_t)a * T_ * B_ + b0 + quad * 4;   // C-layout rows
    const int* dAq = done + (size_t)a * T_ * B_ + b0 + m;           // A-layout row (lane&15)

    ushort4 px0 = xi4[xibase], px1 = xi4[xibase + 64], px2 = xi4[xibase + 128];
    int4 dn = *(const int4*)(dptr);
    int dead = dAq[0];

    for (int t = 0; t < T_; ++t) {
        u16 (*hl)[136] = hlds[t & 1];
        // publish UNRESET ys(t-1) (t=0: hstate); reset register copy for z*h
#pragma unroll
        for (int r = 0; r < 4; ++r) hl[quad * 4 + r][col] = hb[r];
        if (dn.x) hm[0] = 0.f;
        if (dn.y) hm[1] = 0.f;
        if (dn.z) hm[2] = 0.f;
        if (dn.w) hm[3] = 0.f;
        __syncthreads();   // the ONLY barrier per step

        // xi extraction seeds the r/z accumulators; an seeded with bh
        f32x4 ar, az, an;
        float xn[4];
        ar[0] = b2f(px0.x); ar[1] = b2f(px0.y); ar[2] = b2f(px0.z); ar[3] = b2f(px0.w);
        az[0] = b2f(px1.x); az[1] = b2f(px1.y); az[2] = b2f(px1.z); az[3] = b2f(px1.w);
        xn[0] = b2f(px2.x); xn[1] = b2f(px2.y); xn[2] = b2f(px2.z); xn[3] = b2f(px2.w);
        an = f32x4{bh, bh, bh, bh};
        const int deadcur = dead;
        if (t + 1 < T_) {
            const size_t nx = xibase + (size_t)(t + 1) * 1536;
            px0 = xi4[nx]; px1 = xi4[nx + 64]; px2 = xi4[nx + 128];
            dn = *(const int4*)(dptr + (size_t)(t + 1) * B_);
            dead = dAq[(size_t)(t + 1) * B_];
        }

        short8 af[4];
#pragma unroll
        for (int ks = 0; ks < 4; ++ks)
            af[ks] = *(const short8*)&hl[m][ks * 32 + quad * 8];

        // heads first GEMMs on UNRESET ys(t-1)
        f32x4 aa, ac;
        if (t > 0) {
            aa = f32x4{fa, fa, fa, fa};
            ac = f32x4{fc, fc, fc, fc};
#pragma unroll
            for (int ks = 0; ks < 4; ++ks) {
                aa = mfma16(af[ks], wa[ks], aa);
                ac = mfma16(af[ks], wc[ks], ac);
            }
        }

        // done-reset for the Wh path — skipped when no fragment row is dead
        short8 afr[4];
#pragma unroll
        for (int ks = 0; ks < 4; ++ks) afr[ks] = af[ks];
        if (__any(deadcur)) {
            const short8 z8 = short8{0, 0, 0, 0, 0, 0, 0, 0};
#pragma unroll
            for (int ks = 0; ks < 4; ++ks) if (deadcur) afr[ks] = z8;
        }
#pragma unroll
        for (int ks = 0; ks < 4; ++ks) {
            ar = mfma16(afr[ks], wh[0][ks], ar);
            az = mfma16(afr[ks], wh[1][ks], az);
            an = mfma16(afr[ks], wh[2][ks], an);
        }

        // heads tanh -> LDS (read NEXT step; no extra barrier needed)
        if (t > 0) {
#pragma unroll
            for (int r = 0; r < 4; ++r) {
                al[t & 1][0][quad * 4 + r][col] = f2bc(tanh_pre(aa[r]));
                al[t & 1][1][quad * 4 + r][col] = f2bc(tanh_pre(ac[r]));
            }
        }

        // GRU gates (prescaled args)
#pragma unroll
        for (int r = 0; r < 4; ++r) {
            const float rg = sig_pre(ar[r]);
            const float zg = sig_pre(az[r]);
            const float ng = tanh_pre(fmaf(rg, an[r], xn[r]));
            const float hn2 = fmaf(zg, hm[r] - ng, ng);
            hm[r] = hn2;
            hb[r] = f2bc(hn2);
        }

        // deferred heads second GEMM: al[(t-1)&1] -> outputs for timestep t-2
        if (t >= 2 && wid < 2) {
            short8 tf[4];
#pragma unroll
            for (int ks = 0; ks < 4; ++ks)
                tf[ks] = *(const short8*)&al[(t - 1) & 1][wid][m][ks * 32 + quad * 8];
            f32x4 tacc = f32x4{bb2, bb2, bb2, bb2};
#pragma unroll
            for (int ks = 0; ks < 4; ++ks) tacc = mfma16(tf[ks], h2f[ks], tacc);
            const size_t R0 = (size_t)a * 32768 + (size_t)(t - 2) * 256 + b0;
            if (wid == 0) {
                if (m < 8) {
#pragma unroll
                    for (int r = 0; r < 4; ++r)
                        mean_out[(R0 + quad * 4 + r) * 8 + m] = tacc[r];
                }
            } else {
                if (m == 8) {
#pragma unroll
                    for (int r = 0; r < 4; ++r)
                        val_out[R0 + quad * 4 + r] = tacc[r];
                }
            }
        }
    }

#pragma unroll
    for (int r = 0; r < 4; ++r)
        hT_out[((size_t)a * B_ + b0 + quad * 4 + r) * H_ + col] = hm[r];

    // epilogue: heads for ys(T-2) (al[1]) and ys(T-1) (fresh)
    {
        u16 (*hl)[136] = hlds[0];
#pragma unroll
        for (int r = 0; r < 4; ++r) hl[quad * 4 + r][col] = hb[r];
        __syncthreads();
        short8 af[4];
#pragma unroll
        for (int ks = 0; ks < 4; ++ks)
            af[ks] = *(const short8*)&hl[m][ks * 32 + quad * 8];
        f32x4 aa = f32x4{fa, fa, fa, fa};
        f32x4 ac = f32x4{fc, fc, fc, fc};
#pragma unroll
        for (int ks = 0; ks < 4; ++ks) {
            aa = mfma16(af[ks], wa[ks], aa);
            ac = mfma16(af[ks], wc[ks], ac);
        }
#pragma unroll
        for (int r = 0; r < 4; ++r) {
            al[0][0][quad * 4 + r][col] = f2bc(tanh_pre(aa[r]));
            al[0][1][quad * 4 + r][col] = f2bc(tanh_pre(ac[r]));
        }
        // GEMM2 for ys(T-2): al[(T-1)&1] = al[1], written at t=T-1
        if (wid < 2) {
            short8 tf[4];
#pragma unroll
            for (int ks = 0; ks < 4; ++ks)
                tf[ks] = *(const short8*)&al[1][wid][m][ks * 32 + quad * 8];
            f32x4 tacc = f32x4{bb2, bb2, bb2, bb2};
#pragma unroll
            for (int ks = 0; ks < 4; ++ks) tacc = mfma16(tf[ks], h2f[ks], tacc);
            const size_t R0 = (size_t)a * 32768 + (size_t)(T_ - 2) * 256 + b0;
            if (wid == 0) {
                if (m < 8) {
#pragma unroll
                    for (int r = 0; r < 4; ++r)
                        mean_out[(R0 + quad * 4 + r) * 8 + m] = tacc[r];
                }
            } else {
                if (m == 8) {
#pragma unroll
                    for (int r = 0; r < 4; ++r)
                        val_out[R0 + quad * 4 + r] = tacc[r];
                }
            }
        }
        __syncthreads();
        // GEMM2 for ys(T-1): al[0] written above
        if (wid < 2) {
            short8 tf[4];
#pragma unroll
            for (int ks = 0; ks < 4; ++ks)
                tf[ks] = *(const short8*)&al[0][wid][m][ks * 32 + quad * 8];
            f32x4 tacc = f32x4{bb2, bb2, bb2, bb2};
#pragma unroll
            for (int ks = 0; ks < 4; ++ks) tacc = mfma16(tf[ks], h2f[ks], tacc);
            const size_t R0 = (size_t)a * 32768 + (size_t)(T_ - 1) * 256 + b0;
            if (wid == 0) {
                if (m < 8) {
#pragma unroll
                    for (int r = 0; r < 4; ++r)
                        mean_out[(R0 + quad * 4 + r) * 8 + m] = tacc[r];
                }
            } else {
                if (m == 8) {
#pragma unroll
                    for (int r = 0; r < 4; ++r)
                        val_out[R0 + quad * 4 + r] = tacc[r];
                }
            }
        }
    }
}

extern "C" void kernel_launch(void* const* d_in, const int* in_sizes, int n_in,
                              void* d_out, int out_size, void* d_ws, size_t ws_size,
                              hipStream_t stream) {
    const float* hstate = (const float*)d_in[0];
    const float* obs = (const float*)d_in[1];
    const float* We = (const float*)d_in[3];
    const float* be = (const float*)d_in[4];
    const float* Wi = (const float*)d_in[5];
    const float* bi = (const float*)d_in[6];
    const float* Wh = (const float*)d_in[7];
    const float* bhn = (const float*)d_in[8];
    const float* Wa1 = (const float*)d_in[9];
    const float* ba1 = (const float*)d_in[10];
    const float* Wa2 = (const float*)d_in[11];
    const float* ba2 = (const float*)d_in[12];
    const float* log_std = (const float*)d_in[13];
    const float* Wc1 = (const float*)d_in[14];
    const float* bc1 = (const float*)d_in[15];
    const float* Wc2 = (const float*)d_in[16];
    const float* bc2 = (const float*)d_in[17];
    const int* done = (const int*)d_in[18];

    float* out = (float*)d_out;
    float* hT_out = out;                    // (4,256,128)
    float* mean_out = out + 131072;         // (4,128,256,8)
    float* std_out = out + 1179648;         // (4,8)
    float* val_out = out + 1179680;         // (4,128,256)

    u16* ws = (u16*)d_ws;
    u16* xi = ws;
    u16* ys = xi + 50331648;                // region unused (kept for layout)
    u16* weT = ys + 16777216;
    u16* wiT = weT + 65536;
    u16* whT = wiT + 196608;
    u16* wa1T = whT + 196608;
    u16* wc1T = wa1T + 65536;
    u16* h2T = wc1T + 65536;

    hipLaunchKernelGGL(k_prep, dim3(2337), dim3(256), 0, stream,
                       We, Wi, Wh, Wa1, Wc1, Wa2, Wc2, log_std,
                       weT, wiT, whT, wa1T, wc1T, h2T, std_out);
    hipLaunchKernelGGL(k_embed_xi, dim3(128, 4, 2), dim3(512), 0, stream,
                       obs, be, bi, weT, wiT, xi);
    hipLaunchKernelGGL(k_scan, dim3(16, 4), dim3(512), 0, stream,
                       hstate, xi, whT, bhn, done,
                       wa1T, wc1T, h2T, ba1, bc1, ba2, bc2,
                       hT_out, mean_out, val_out);
}